// Round 6
// baseline (262.964 us; speedup 1.0000x reference)
//
#include <hip/hip_runtime.h>
#include <cmath>

typedef short bf16x8 __attribute__((ext_vector_type(8)));
typedef float f32x4 __attribute__((ext_vector_type(4)));

#define T_DIM 1024

__device__ __forceinline__ unsigned short rtn_bf16(float f) {
    unsigned u = __float_as_uint(f);
    return (unsigned short)((u + 0x7FFFu + ((u >> 16) & 1u)) >> 16);
}
__device__ __forceinline__ float bf_to_f(unsigned short h) {
    return __uint_as_float(((unsigned)h) << 16);
}
// Truncation-based exact 3-limb split (subtracting a truncation is exact in fp32)
__device__ __forceinline__ void split3(float f, unsigned short& h1,
                                       unsigned short& h2, unsigned short& h3) {
    unsigned u = __float_as_uint(f);
    h1 = (unsigned short)(u >> 16);
    float r1 = f - __uint_as_float(u & 0xFFFF0000u);
    unsigned u1 = __float_as_uint(r1);
    h2 = (unsigned short)(u1 >> 16);
    float r2 = r1 - __uint_as_float(u1 & 0xFFFF0000u);
    h3 = rtn_bf16(r2);
}

// ---------------------------------------------------------------------------
// Kernel 0: split w (fp32 [k][n]) into 3 bf16 limbs, TRANSPOSED: wT[n][k].
// ---------------------------------------------------------------------------
__global__ __launch_bounds__(256) void lif_wsplit(const float* __restrict__ w,
                                                  unsigned short* __restrict__ wT1,
                                                  unsigned short* __restrict__ wT2,
                                                  unsigned short* __restrict__ wT3) {
    const int id = blockIdx.x * 256 + threadIdx.x;
    const int k = id >> 8, n = id & 255;
    unsigned short h1, h2, h3;
    split3(w[id], h1, h2, h3);
    const int o = n * 256 + k;
    wT1[o] = h1; wT2[o] = h2; wT3[o] = h3;
}

// ---------------------------------------------------------------------------
// Kernel 1: bf16-MFMA GEMM. A fp32 in LDS (split to limbs at read time),
// W limb tiles in LDS (staged per kt from wT) -> no vmcnt waits in K-loop.
// Block 128m x 128n, BK=64, 4 waves each 64x64. grid (512, 2).
// LDS = A 32 KiB + W 48 KiB = 80 KiB -> 2 blocks/CU.
// Both arrays use 16B-chunk XOR swizzle -> conflict-free b128 access.
// ---------------------------------------------------------------------------
__global__ __launch_bounds__(256) void lif_gemm_mfma(const float* __restrict__ in,
                                                     const unsigned short* __restrict__ wT1,
                                                     const unsigned short* __restrict__ wT2,
                                                     const unsigned short* __restrict__ wT3,
                                                     float* __restrict__ xbuf) {
    __shared__ float          As[128 * 64];        // fp32 A tile, 16B chunks swz ^ (row&15)
    __shared__ unsigned short WL[3 * 128 * 64];    // W limb tiles, 16B chunks swz ^ (row&7)

    const int tid  = threadIdx.x;
    const int bm   = blockIdx.x;           // 0..511
    const int bn   = blockIdx.y;           // 0..1
    const int wave = tid >> 6;
    const int lane = tid & 63;
    const int l15  = lane & 15;
    const int quad = lane >> 4;
    const int wm   = (wave >> 1) * 64;
    const int wn   = (wave & 1) * 64;

    f32x4 acc[4][4];
    #pragma unroll
    for (int i = 0; i < 4; ++i)
        #pragma unroll
        for (int j = 0; j < 4; ++j) acc[i][j] = (f32x4){0.f, 0.f, 0.f, 0.f};

    const int r  = tid >> 1;               // A staging row 0..127
    const int hf = tid & 1;                // A staging k-half
    const float* arow = in + (size_t)(bm * 128 + r) * 256 + hf * 32;
    const unsigned short* wTs[3] = {wT1, wT2, wT3};

    for (int kt = 0; kt < 4; ++kt) {
        const int k0 = kt * 64;
        // A prefetch to regs (8 float4 per thread)
        float4 av[8];
        #pragma unroll
        for (int j = 0; j < 8; ++j)
            av[j] = *(const float4*)(arow + k0 + j * 4);

        __syncthreads();                   // previous tile fully consumed
        // store A (16B chunks, swz = chunk ^ (row&15); chunk = hf*8 + j)
        #pragma unroll
        for (int j = 0; j < 8; ++j) {
            const int sw = ((hf * 8 + j) ^ (r & 15)) * 4;
            *(float4*)&As[r * 64 + sw] = av[j];
        }
        // stage W: 3072 16B-chunks, 12 per thread (coalesced over tid)
        #pragma unroll
        for (int j = 0; j < 12; ++j) {
            const int c    = j * 256 + tid;
            const int limb = c >> 10;
            const int rem  = c & 1023;
            const int nl   = rem >> 3;     // 0..127
            const int ch   = rem & 7;      // 0..7 (8-half chunks)
            const unsigned short* src = wTs[limb] + (size_t)(bn * 128 + nl) * 256 + k0 + ch * 8;
            *(bf16x8*)&WL[limb * 8192 + nl * 64 + ((ch ^ (nl & 7)) * 8)] = *(const bf16x8*)src;
        }
        __syncthreads();

        #pragma unroll
        for (int ks = 0; ks < 2; ++ks) {
            // A fragments: lane needs A[m=l15-row][k=ks*32+quad*8 ..+7] (2 swizzled chunks)
            bf16x8 af[3][4];
            #pragma unroll
            for (int mt = 0; mt < 4; ++mt) {
                const int m = wm + mt * 16 + l15;
                const int cbase = 2 * (ks * 4 + quad);
                float4 f0 = *(const float4*)&As[m * 64 + ((cbase    ) ^ l15) * 4];
                float4 f1 = *(const float4*)&As[m * 64 + ((cbase + 1) ^ l15) * 4];
                const float fv[8] = {f0.x, f0.y, f0.z, f0.w, f1.x, f1.y, f1.z, f1.w};
                #pragma unroll
                for (int i = 0; i < 8; ++i) {
                    unsigned short h1, h2, h3;
                    split3(fv[i], h1, h2, h3);
                    af[0][mt][i] = (short)h1;
                    af[1][mt][i] = (short)h2;
                    af[2][mt][i] = (short)h3;
                }
            }
            #pragma unroll
            for (int nt = 0; nt < 4; ++nt) {
                const int nl = wn + nt * 16 + l15;
                const int wo = nl * 64 + (((ks * 4 + quad) ^ (nl & 7)) * 8);
                const bf16x8 b1 = *(const bf16x8*)&WL[          wo];
                const bf16x8 b2 = *(const bf16x8*)&WL[ 8192 +   wo];
                const bf16x8 b3 = *(const bf16x8*)&WL[16384 +   wo];
                #pragma unroll
                for (int mt = 0; mt < 4; ++mt) {
                    f32x4 a = acc[mt][nt];
                    a = __builtin_amdgcn_mfma_f32_16x16x32_bf16(af[0][mt], b1, a, 0, 0, 0);
                    a = __builtin_amdgcn_mfma_f32_16x16x32_bf16(af[0][mt], b2, a, 0, 0, 0);
                    a = __builtin_amdgcn_mfma_f32_16x16x32_bf16(af[1][mt], b1, a, 0, 0, 0);
                    a = __builtin_amdgcn_mfma_f32_16x16x32_bf16(af[1][mt], b2, a, 0, 0, 0);
                    a = __builtin_amdgcn_mfma_f32_16x16x32_bf16(af[0][mt], b3, a, 0, 0, 0);
                    a = __builtin_amdgcn_mfma_f32_16x16x32_bf16(af[2][mt], b1, a, 0, 0, 0);
                    acc[mt][nt] = a;
                }
            }
        }
    }

    // epilogue: C/D layout col=lane&15, row=quad*4+reg
    #pragma unroll
    for (int mt = 0; mt < 4; ++mt) {
        #pragma unroll
        for (int nt = 0; nt < 4; ++nt) {
            const int C  = bn * 128 + wn + nt * 16 + l15;
            const int Rb = bm * 128 + wm + mt * 16 + quad * 4;
            #pragma unroll
            for (int reg = 0; reg < 4; ++reg)
                xbuf[(size_t)(Rb + reg) * 256 + C] = acc[mt][nt][reg];
        }
    }
}

// ---------------------------------------------------------------------------
// Kernel 2: LIF scan. One thread per (b,o), fp64 state. 256 blocks x 64 thr.
// Register ping-pong: batch c+1's 32 loads issue BEFORE batch c is consumed,
// hiding HBM latency behind the fp64 chain. NT loads/stores spare L2.
// ---------------------------------------------------------------------------
__global__ __launch_bounds__(64) void lif_scan(const float* __restrict__ xbuf,
                                               float* __restrict__ U,
                                               double dcy_syn, double dcy_mem,
                                               double scl_mem) {
    const int b = blockIdx.x >> 2;
    const int o = (blockIdx.x & 3) * 64 + threadIdx.x;

    const float* xp = xbuf + (size_t)b * T_DIM * 256 + o;
    float* up = U + (size_t)b * T_DIM * 256 + o;

    up[0] = 0.0f;                          // U[b][0][o] = initial state
    double syn = 0.0, mem = 0.0;

    float xr[2][32];
    #pragma unroll
    for (int j = 0; j < 32; ++j)
        xr[0][j] = __builtin_nontemporal_load(xp + (size_t)j * 256);

    for (int bt = 0; bt < 32; ++bt) {
        const int cur = bt & 1;
        if (bt < 31) {                     // prefetch next batch (in flight during compute)
            const float* np = xp + (size_t)(bt + 1) * 32 * 256;
            #pragma unroll
            for (int j = 0; j < 32; ++j)
                xr[cur ^ 1][j] = __builtin_nontemporal_load(np + (size_t)j * 256);
        }
        const int tb = bt * 32;
        #pragma unroll
        for (int j = 0; j < 32; ++j) {
            const int t = tb + j;
            if (t < T_DIM - 1) {           // steps t = 0..1022
                double nm = dcy_mem * mem + scl_mem * syn;
                if (mem - 1.0 > 0.0) nm = 0.0;
                syn = dcy_syn * syn + (double)xr[cur][j];
                mem = nm;
                __builtin_nontemporal_store((float)mem, up + (size_t)(t + 1) * 256);
            }
        }
    }
}

extern "C" void kernel_launch(void* const* d_in, const int* in_sizes, int n_in,
                              void* d_out, int out_size, void* d_ws, size_t ws_size,
                              hipStream_t stream) {
    const float* in = (const float*)d_in[0];   // fp32 [64][1024][256]
    const float* w  = (const float*)d_in[1];   // fp32 [256][256]
    float* U = (float*)d_out;                  // fp32 [64][1024][256]

    const double dcy_mem = exp(-0.001 / (0.01  + 1e-16));
    const double dcy_syn = exp(-0.001 / (0.005 + 1e-16));
    const double scl_mem = 1.0 - dcy_mem;

    // ws layout: wT1|wT2|wT3 (3 x 128 KiB bf16) | xbuf (64 MiB fp32)
    char* ws = (char*)d_ws;
    unsigned short* wT1 = (unsigned short*)ws;
    unsigned short* wT2 = (unsigned short*)(ws + 131072);
    unsigned short* wT3 = (unsigned short*)(ws + 262144);
    float* xbuf = (float*)(ws + 524288);

    lif_wsplit<<<dim3(256), dim3(256), 0, stream>>>(w, wT1, wT2, wT3);
    lif_gemm_mfma<<<dim3(512, 2), dim3(256), 0, stream>>>(in, wT1, wT2, wT3, xbuf);
    lif_scan<<<dim3(256), dim3(64), 0, stream>>>(xbuf, U, dcy_syn, dcy_mem, scl_mem);
}

// Round 7
// 199.725 us; speedup vs baseline: 1.3166x; 1.3166x over previous
//
#include <hip/hip_runtime.h>
#include <cmath>

typedef short bf16x8 __attribute__((ext_vector_type(8)));
typedef float f32x4 __attribute__((ext_vector_type(4)));
typedef unsigned short us8v __attribute__((ext_vector_type(8)));

#define T_DIM 1024

__device__ __forceinline__ unsigned short rtn_bf16(float f) {
    unsigned u = __float_as_uint(f);
    return (unsigned short)((u + 0x7FFFu + ((u >> 16) & 1u)) >> 16);
}
__device__ __forceinline__ float bf_to_f(unsigned short h) {
    return __uint_as_float(((unsigned)h) << 16);
}
// Truncation-based exact 3-limb split (subtracting a truncation is exact in fp32)
__device__ __forceinline__ void split3(float f, unsigned short& h1,
                                       unsigned short& h2, unsigned short& h3) {
    unsigned u = __float_as_uint(f);
    h1 = (unsigned short)(u >> 16);
    float r1 = f - __uint_as_float(u & 0xFFFF0000u);
    unsigned u1 = __float_as_uint(r1);
    h2 = (unsigned short)(u1 >> 16);
    float r2 = r1 - __uint_as_float(u1 & 0xFFFF0000u);
    h3 = rtn_bf16(r2);
}

// ---------------------------------------------------------------------------
// Kernel 0: split w (fp32 [k][n]) into 3 bf16 limbs, TRANSPOSED: wT[n][k].
// ---------------------------------------------------------------------------
__global__ __launch_bounds__(256) void lif_wsplit(const float* __restrict__ w,
                                                  unsigned short* __restrict__ wT1,
                                                  unsigned short* __restrict__ wT2,
                                                  unsigned short* __restrict__ wT3) {
    const int id = blockIdx.x * 256 + threadIdx.x;
    const int k = id >> 8, n = id & 255;
    unsigned short h1, h2, h3;
    split3(w[id], h1, h2, h3);
    const int o = n * 256 + k;
    wT1[o] = h1; wT2[o] = h2; wT3[o] = h3;
}

// ---------------------------------------------------------------------------
// Kernel 1: bf16-MFMA GEMM (R5 structure: A limbs in LDS, B from global wT)
// + one-nt-ahead B-fragment register prefetch to hide L2 latency under MFMAs.
// 6 MFMA products: a1w1,a1w2,a2w1,a2w2,a1w3,a3w1.
// Block 128m x 128n, BK=64, 4 waves each 64x64. grid (512, 2).
// LDS 48 KiB, 16B-chunk XOR swizzle (measured 0 bank conflicts in R5).
// ---------------------------------------------------------------------------
__global__ __launch_bounds__(256) void lif_gemm_mfma(const float* __restrict__ in,
                                                     const unsigned short* __restrict__ wT1,
                                                     const unsigned short* __restrict__ wT2,
                                                     const unsigned short* __restrict__ wT3,
                                                     float* __restrict__ xbuf) {
    __shared__ unsigned short As[3][128 * 64];   // 3 limb tiles, 48 KiB

    const int tid  = threadIdx.x;
    const int bm   = blockIdx.x;           // 0..511
    const int bn   = blockIdx.y;           // 0..1
    const int wave = tid >> 6;
    const int lane = tid & 63;
    const int l15  = lane & 15;
    const int quad = lane >> 4;
    const int wm   = (wave >> 1) * 64;
    const int wn   = (wave & 1) * 64;

    f32x4 acc[4][4];
    #pragma unroll
    for (int i = 0; i < 4; ++i)
        #pragma unroll
        for (int j = 0; j < 4; ++j) acc[i][j] = (f32x4){0.f, 0.f, 0.f, 0.f};

    const int r  = tid >> 1;               // staging row 0..127
    const int hf = tid & 1;                // staging k-half (32 floats)
    const int rx = r & 7;                  // XOR swizzle key
    const float* arow = in + (size_t)(bm * 128 + r) * 256 + hf * 32;

    for (int kt = 0; kt < 4; ++kt) {
        const int k0 = kt * 64;
        // prefetch this chunk's A data to registers before the barrier
        float4 av[8];
        #pragma unroll
        for (int j = 0; j < 8; ++j)
            av[j] = *(const float4*)(arow + k0 + j * 4);

        __syncthreads();                   // previous chunk fully consumed
        #pragma unroll
        for (int j2 = 0; j2 < 4; ++j2) {
            const float fv[8] = {av[2*j2].x, av[2*j2].y, av[2*j2].z, av[2*j2].w,
                                 av[2*j2+1].x, av[2*j2+1].y, av[2*j2+1].z, av[2*j2+1].w};
            us8v o1, o2, o3;
            #pragma unroll
            for (int i = 0; i < 8; ++i) {
                unsigned short h1, h2, h3;
                split3(fv[i], h1, h2, h3);
                o1[i] = h1; o2[i] = h2; o3[i] = h3;
            }
            const int cp = ((hf * 4 + j2) ^ rx) * 8;      // swizzled chunk offset
            *(us8v*)&As[0][r * 64 + cp] = o1;
            *(us8v*)&As[1][r * 64 + cp] = o2;
            *(us8v*)&As[2][r * 64 + cp] = o3;
        }
        __syncthreads();

        #pragma unroll
        for (int ks = 0; ks < 2; ++ks) {
            // A fragments: A[m=l15][k=quad*8+j], swizzled chunk
            bf16x8 af[3][4];
            const int ko = ((ks * 4 + quad) ^ (l15 & 7)) * 8;
            #pragma unroll
            for (int mt = 0; mt < 4; ++mt) {
                const int ro = (wm + mt * 16 + l15) * 64 + ko;
                af[0][mt] = *(const bf16x8*)&As[0][ro];
                af[1][mt] = *(const bf16x8*)&As[1][ro];
                af[2][mt] = *(const bf16x8*)&As[2][ro];
            }

            // B software pipeline: preload nt=0, then prefetch nt+1 during
            // nt's MFMAs (fully unrolled -> SSA renaming, no dynamic arrays)
            size_t wo = (size_t)(bn * 128 + wn + l15) * 256 + k0 + ks * 32 + quad * 8;
            bf16x8 b1 = *(const bf16x8*)(wT1 + wo);
            bf16x8 b2 = *(const bf16x8*)(wT2 + wo);
            bf16x8 b3 = *(const bf16x8*)(wT3 + wo);

            #pragma unroll
            for (int nt = 0; nt < 4; ++nt) {
                bf16x8 n1, n2, n3;
                if (nt < 3) {
                    const size_t won = wo + (size_t)16 * 256;   // next ncol = +16
                    n1 = *(const bf16x8*)(wT1 + won);
                    n2 = *(const bf16x8*)(wT2 + won);
                    n3 = *(const bf16x8*)(wT3 + won);
                }
                #pragma unroll
                for (int mt = 0; mt < 4; ++mt) {
                    f32x4 a = acc[mt][nt];
                    a = __builtin_amdgcn_mfma_f32_16x16x32_bf16(af[0][mt], b1, a, 0, 0, 0);
                    a = __builtin_amdgcn_mfma_f32_16x16x32_bf16(af[0][mt], b2, a, 0, 0, 0);
                    a = __builtin_amdgcn_mfma_f32_16x16x32_bf16(af[1][mt], b1, a, 0, 0, 0);
                    a = __builtin_amdgcn_mfma_f32_16x16x32_bf16(af[1][mt], b2, a, 0, 0, 0);
                    a = __builtin_amdgcn_mfma_f32_16x16x32_bf16(af[0][mt], b3, a, 0, 0, 0);
                    a = __builtin_amdgcn_mfma_f32_16x16x32_bf16(af[2][mt], b1, a, 0, 0, 0);
                    acc[mt][nt] = a;
                }
                if (nt < 3) { b1 = n1; b2 = n2; b3 = n3; wo += (size_t)16 * 256; }
            }
        }
    }

    // epilogue: C/D layout col=lane&15, row=quad*4+reg
    #pragma unroll
    for (int mt = 0; mt < 4; ++mt) {
        #pragma unroll
        for (int nt = 0; nt < 4; ++nt) {
            const int C  = bn * 128 + wn + nt * 16 + l15;
            const int Rb = bm * 128 + wm + mt * 16 + quad * 4;
            #pragma unroll
            for (int reg = 0; reg < 4; ++reg)
                xbuf[(size_t)(Rb + reg) * 256 + C] = acc[mt][nt][reg];
        }
    }
}

// ---------------------------------------------------------------------------
// Kernel 2: LIF scan. One thread per (b,o), fp64 state. 256 blocks x 64 thr.
// TWO static buffers, phase-structured (all indices compile-time after
// unroll -> registers, NOT scratch). Batch c+1's loads in flight during c.
// ---------------------------------------------------------------------------
__global__ __launch_bounds__(64) void lif_scan(const float* __restrict__ xbuf,
                                               float* __restrict__ U,
                                               double dcy_syn, double dcy_mem,
                                               double scl_mem) {
    const int b = blockIdx.x >> 2;
    const int o = (blockIdx.x & 3) * 64 + threadIdx.x;

    const float* xp = xbuf + (size_t)b * T_DIM * 256 + o;
    float* up = U + (size_t)b * T_DIM * 256 + o;

    up[0] = 0.0f;                          // U[b][0][o] = initial state
    double syn = 0.0, mem = 0.0;

    float bufA[32], bufB[32];
    #pragma unroll
    for (int j = 0; j < 32; ++j)
        bufA[j] = __builtin_nontemporal_load(xp + (size_t)j * 256);

    #pragma unroll 1
    for (int bt = 0; bt < 16; ++bt) {      // 16 x (2 batches of 32) = 1024 steps
        const int tb = bt * 64;
        // phase A: prefetch next batch into B, consume A
        {
            const float* np = xp + (size_t)(tb + 32) * 256;
            #pragma unroll
            for (int j = 0; j < 32; ++j)
                bufB[j] = __builtin_nontemporal_load(np + (size_t)j * 256);
        }
        #pragma unroll
        for (int j = 0; j < 32; ++j) {
            const int t = tb + j;
            double nm = dcy_mem * mem + scl_mem * syn;
            if (mem - 1.0 > 0.0) nm = 0.0;
            syn = dcy_syn * syn + (double)bufA[j];
            mem = nm;
            __builtin_nontemporal_store((float)mem, up + (size_t)(t + 1) * 256);
        }
        // phase B: prefetch next batch into A (guard last), consume B
        if (bt < 15) {
            const float* np = xp + (size_t)(tb + 64) * 256;
            #pragma unroll
            for (int j = 0; j < 32; ++j)
                bufA[j] = __builtin_nontemporal_load(np + (size_t)j * 256);
        }
        #pragma unroll
        for (int j = 0; j < 32; ++j) {
            const int t = tb + 32 + j;
            double nm = dcy_mem * mem + scl_mem * syn;
            if (mem - 1.0 > 0.0) nm = 0.0;
            syn = dcy_syn * syn + (double)bufB[j];
            mem = nm;
            if (t < T_DIM - 1)             // skip only the final t=1023 store
                __builtin_nontemporal_store((float)mem, up + (size_t)(t + 1) * 256);
        }
    }
}

extern "C" void kernel_launch(void* const* d_in, const int* in_sizes, int n_in,
                              void* d_out, int out_size, void* d_ws, size_t ws_size,
                              hipStream_t stream) {
    const float* in = (const float*)d_in[0];   // fp32 [64][1024][256]
    const float* w  = (const float*)d_in[1];   // fp32 [256][256]
    float* U = (float*)d_out;                  // fp32 [64][1024][256]

    const double dcy_mem = exp(-0.001 / (0.01  + 1e-16));
    const double dcy_syn = exp(-0.001 / (0.005 + 1e-16));
    const double scl_mem = 1.0 - dcy_mem;

    // ws layout: wT1|wT2|wT3 (3 x 128 KiB bf16) | xbuf (64 MiB fp32)
    char* ws = (char*)d_ws;
    unsigned short* wT1 = (unsigned short*)ws;
    unsigned short* wT2 = (unsigned short*)(ws + 131072);
    unsigned short* wT3 = (unsigned short*)(ws + 262144);
    float* xbuf = (float*)(ws + 524288);

    lif_wsplit<<<dim3(256), dim3(256), 0, stream>>>(w, wT1, wT2, wT3);
    lif_gemm_mfma<<<dim3(512, 2), dim3(256), 0, stream>>>(in, wT1, wT2, wT3, xbuf);
    lif_scan<<<dim3(256), dim3(64), 0, stream>>>(xbuf, U, dcy_syn, dcy_mem, scl_mem);
}

// Round 8
// 198.558 us; speedup vs baseline: 1.3244x; 1.0059x over previous
//
#include <hip/hip_runtime.h>
#include <cmath>

typedef short bf16x8 __attribute__((ext_vector_type(8)));
typedef float f32x4 __attribute__((ext_vector_type(4)));
typedef unsigned short us8v __attribute__((ext_vector_type(8)));

#define T_DIM 1024

__device__ __forceinline__ unsigned short rtn_bf16(float f) {
    unsigned u = __float_as_uint(f);
    return (unsigned short)((u + 0x7FFFu + ((u >> 16) & 1u)) >> 16);
}
__device__ __forceinline__ float bf_to_f(unsigned short h) {
    return __uint_as_float(((unsigned)h) << 16);
}
// Truncation-based exact 3-limb split (subtracting a truncation is exact in fp32)
__device__ __forceinline__ void split3(float f, unsigned short& h1,
                                       unsigned short& h2, unsigned short& h3) {
    unsigned u = __float_as_uint(f);
    h1 = (unsigned short)(u >> 16);
    float r1 = f - __uint_as_float(u & 0xFFFF0000u);
    unsigned u1 = __float_as_uint(r1);
    h2 = (unsigned short)(u1 >> 16);
    float r2 = r1 - __uint_as_float(u1 & 0xFFFF0000u);
    h3 = rtn_bf16(r2);
}

// ---------------------------------------------------------------------------
// Kernel 0: split w (fp32 [k][n]) into 3 bf16 limbs, TRANSPOSED: wT[n][k].
// ---------------------------------------------------------------------------
__global__ __launch_bounds__(256) void lif_wsplit(const float* __restrict__ w,
                                                  unsigned short* __restrict__ wT1,
                                                  unsigned short* __restrict__ wT2,
                                                  unsigned short* __restrict__ wT3) {
    const int id = blockIdx.x * 256 + threadIdx.x;
    const int k = id >> 8, n = id & 255;
    unsigned short h1, h2, h3;
    split3(w[id], h1, h2, h3);
    const int o = n * 256 + k;
    wT1[o] = h1; wT2[o] = h2; wT3[o] = h3;
}

// ---------------------------------------------------------------------------
// Kernel 1: bf16-MFMA GEMM. R7 structure but BK=32: LDS 24 KiB -> ~4 blocks/CU
// (was 48 KiB / ~2) so barrier drains and L2 latency overlap across blocks.
// K-chunk order identical to R7 -> bit-identical accumulation.
// 6 MFMA products: a1w1,a1w2,a2w1,a2w2,a1w3,a3w1.
// Block 128m x 128n, 4 waves each 64x64. grid (512, 2).
// 16B-chunk XOR swizzle in LDS (minimum-depth bank access, measured 0 confl).
// ---------------------------------------------------------------------------
__global__ __launch_bounds__(256) void lif_gemm_mfma(const float* __restrict__ in,
                                                     const unsigned short* __restrict__ wT1,
                                                     const unsigned short* __restrict__ wT2,
                                                     const unsigned short* __restrict__ wT3,
                                                     float* __restrict__ xbuf) {
    __shared__ unsigned short As[3][128 * 32];   // 3 limb tiles, 24 KiB

    const int tid  = threadIdx.x;
    const int bm   = blockIdx.x;           // 0..511
    const int bn   = blockIdx.y;           // 0..1
    const int wave = tid >> 6;
    const int lane = tid & 63;
    const int l15  = lane & 15;
    const int quad = lane >> 4;
    const int wm   = (wave >> 1) * 64;
    const int wn   = (wave & 1) * 64;

    f32x4 acc[4][4];
    #pragma unroll
    for (int i = 0; i < 4; ++i)
        #pragma unroll
        for (int j = 0; j < 4; ++j) acc[i][j] = (f32x4){0.f, 0.f, 0.f, 0.f};

    const int r  = tid >> 1;               // staging row 0..127
    const int hf = tid & 1;                // staging k-half (16 floats)
    const int rx = r & 3;                  // XOR swizzle key (4 chunks/row)
    const float* arow = in + (size_t)(bm * 128 + r) * 256 + hf * 16;

    for (int kt = 0; kt < 8; ++kt) {       // 8 x BK=32
        const int k0 = kt * 32;
        // prefetch this chunk's A data to registers before the barrier
        float4 av[4];
        #pragma unroll
        for (int j = 0; j < 4; ++j)
            av[j] = *(const float4*)(arow + k0 + j * 4);

        __syncthreads();                   // previous tile fully consumed
        #pragma unroll
        for (int j2 = 0; j2 < 2; ++j2) {
            const float fv[8] = {av[2*j2].x, av[2*j2].y, av[2*j2].z, av[2*j2].w,
                                 av[2*j2+1].x, av[2*j2+1].y, av[2*j2+1].z, av[2*j2+1].w};
            us8v o1, o2, o3;
            #pragma unroll
            for (int i = 0; i < 8; ++i) {
                unsigned short h1, h2, h3;
                split3(fv[i], h1, h2, h3);
                o1[i] = h1; o2[i] = h2; o3[i] = h3;
            }
            const int cp = ((hf * 2 + j2) ^ rx) * 8;      // swizzled chunk offset
            *(us8v*)&As[0][r * 32 + cp] = o1;
            *(us8v*)&As[1][r * 32 + cp] = o2;
            *(us8v*)&As[2][r * 32 + cp] = o3;
        }
        __syncthreads();

        // A fragments: A[m=l15][k=quad*8+j], swizzled chunk
        bf16x8 af[3][4];
        #pragma unroll
        for (int mt = 0; mt < 4; ++mt) {
            const int m  = wm + mt * 16 + l15;
            const int ro = m * 32 + ((quad ^ (m & 3)) * 8);
            af[0][mt] = *(const bf16x8*)&As[0][ro];
            af[1][mt] = *(const bf16x8*)&As[1][ro];
            af[2][mt] = *(const bf16x8*)&As[2][ro];
        }

        // B software pipeline: preload nt=0, prefetch nt+1 during nt's MFMAs
        size_t wo = (size_t)(bn * 128 + wn + l15) * 256 + k0 + quad * 8;
        bf16x8 b1 = *(const bf16x8*)(wT1 + wo);
        bf16x8 b2 = *(const bf16x8*)(wT2 + wo);
        bf16x8 b3 = *(const bf16x8*)(wT3 + wo);

        #pragma unroll
        for (int nt = 0; nt < 4; ++nt) {
            bf16x8 n1, n2, n3;
            if (nt < 3) {
                const size_t won = wo + (size_t)16 * 256;   // next ncol = +16
                n1 = *(const bf16x8*)(wT1 + won);
                n2 = *(const bf16x8*)(wT2 + won);
                n3 = *(const bf16x8*)(wT3 + won);
            }
            #pragma unroll
            for (int mt = 0; mt < 4; ++mt) {
                f32x4 a = acc[mt][nt];
                a = __builtin_amdgcn_mfma_f32_16x16x32_bf16(af[0][mt], b1, a, 0, 0, 0);
                a = __builtin_amdgcn_mfma_f32_16x16x32_bf16(af[0][mt], b2, a, 0, 0, 0);
                a = __builtin_amdgcn_mfma_f32_16x16x32_bf16(af[1][mt], b1, a, 0, 0, 0);
                a = __builtin_amdgcn_mfma_f32_16x16x32_bf16(af[1][mt], b2, a, 0, 0, 0);
                a = __builtin_amdgcn_mfma_f32_16x16x32_bf16(af[0][mt], b3, a, 0, 0, 0);
                a = __builtin_amdgcn_mfma_f32_16x16x32_bf16(af[2][mt], b1, a, 0, 0, 0);
                acc[mt][nt] = a;
            }
            if (nt < 3) { b1 = n1; b2 = n2; b3 = n3; wo += (size_t)16 * 256; }
        }
    }

    // epilogue: C/D layout col=lane&15, row=quad*4+reg
    #pragma unroll
    for (int mt = 0; mt < 4; ++mt) {
        #pragma unroll
        for (int nt = 0; nt < 4; ++nt) {
            const int C  = bn * 128 + wn + nt * 16 + l15;
            const int Rb = bm * 128 + wm + mt * 16 + quad * 4;
            #pragma unroll
            for (int reg = 0; reg < 4; ++reg)
                xbuf[(size_t)(Rb + reg) * 256 + C] = acc[mt][nt][reg];
        }
    }
}

// ---------------------------------------------------------------------------
// Kernel 2: LIF scan. One thread per (b,o), fp64 state. 256 blocks x 64 thr.
// __launch_bounds__(64, 1): min 1 wave/EU -> full VGPR budget, so the two
// 32-float ping-pong buffers stay in REGISTERS (R3-R7 were scratch-spilled
// by the default occupancy target's ~64-VGPR cap).
// ---------------------------------------------------------------------------
__global__ __launch_bounds__(64, 1) void lif_scan(const float* __restrict__ xbuf,
                                                  float* __restrict__ U,
                                                  double dcy_syn, double dcy_mem,
                                                  double scl_mem) {
    const int b = blockIdx.x >> 2;
    const int o = (blockIdx.x & 3) * 64 + threadIdx.x;

    const float* xp = xbuf + (size_t)b * T_DIM * 256 + o;
    float* up = U + (size_t)b * T_DIM * 256 + o;

    up[0] = 0.0f;                          // U[b][0][o] = initial state
    double syn = 0.0, mem = 0.0;

    float bufA[32], bufB[32];
    #pragma unroll
    for (int j = 0; j < 32; ++j)
        bufA[j] = __builtin_nontemporal_load(xp + (size_t)j * 256);

    #pragma unroll 1
    for (int bt = 0; bt < 16; ++bt) {      // 16 x (2 batches of 32) = 1024 steps
        const int tb = bt * 64;
        // phase A: prefetch next batch into B, consume A
        {
            const float* np = xp + (size_t)(tb + 32) * 256;
            #pragma unroll
            for (int j = 0; j < 32; ++j)
                bufB[j] = __builtin_nontemporal_load(np + (size_t)j * 256);
        }
        #pragma unroll
        for (int j = 0; j < 32; ++j) {
            const int t = tb + j;
            double nm = dcy_mem * mem + scl_mem * syn;
            if (mem - 1.0 > 0.0) nm = 0.0;
            syn = dcy_syn * syn + (double)bufA[j];
            mem = nm;
            up[(size_t)(t + 1) * 256] = (float)mem;
        }
        // phase B: prefetch next batch into A (guard last), consume B
        if (bt < 15) {
            const float* np = xp + (size_t)(tb + 64) * 256;
            #pragma unroll
            for (int j = 0; j < 32; ++j)
                bufA[j] = __builtin_nontemporal_load(np + (size_t)j * 256);
        }
        #pragma unroll
        for (int j = 0; j < 32; ++j) {
            const int t = tb + 32 + j;
            double nm = dcy_mem * mem + scl_mem * syn;
            if (mem - 1.0 > 0.0) nm = 0.0;
            syn = dcy_syn * syn + (double)bufB[j];
            mem = nm;
            if (t < T_DIM - 1)             // skip only the final t=1023 store
                up[(size_t)(t + 1) * 256] = (float)mem;
        }
    }
}

extern "C" void kernel_launch(void* const* d_in, const int* in_sizes, int n_in,
                              void* d_out, int out_size, void* d_ws, size_t ws_size,
                              hipStream_t stream) {
    const float* in = (const float*)d_in[0];   // fp32 [64][1024][256]
    const float* w  = (const float*)d_in[1];   // fp32 [256][256]
    float* U = (float*)d_out;                  // fp32 [64][1024][256]

    const double dcy_mem = exp(-0.001 / (0.01  + 1e-16));
    const double dcy_syn = exp(-0.001 / (0.005 + 1e-16));
    const double scl_mem = 1.0 - dcy_mem;

    // ws layout: wT1|wT2|wT3 (3 x 128 KiB bf16) | xbuf (64 MiB fp32)
    char* ws = (char*)d_ws;
    unsigned short* wT1 = (unsigned short*)ws;
    unsigned short* wT2 = (unsigned short*)(ws + 131072);
    unsigned short* wT3 = (unsigned short*)(ws + 262144);
    float* xbuf = (float*)(ws + 524288);

    lif_wsplit<<<dim3(256), dim3(256), 0, stream>>>(w, wT1, wT2, wT3);
    lif_gemm_mfma<<<dim3(512, 2), dim3(256), 0, stream>>>(in, wT1, wT2, wT3, xbuf);
    lif_scan<<<dim3(256), dim3(64), 0, stream>>>(xbuf, U, dcy_syn, dcy_mem, scl_mem);
}